// Round 2
// baseline (1107.440 us; speedup 1.0000x reference)
//
#include <hip/hip_runtime.h>

typedef unsigned int u32;

#define DEV static __device__ __forceinline__

DEV float ex2(float x){ return __builtin_amdgcn_exp2f(x); }
DEV float rcpf_(float x){ return __builtin_amdgcn_rcpf(x); }

DEV float tanh_f(float x){
    x = fminf(12.f, fmaxf(-12.f, x));
    float t = ex2(x*2.885390082f);          // e^(2x) = 2^(2x*log2(e))
    return (t-1.f)*rcpf_(t+1.f);
}
DEV float sigm(float x){
    x = fminf(30.f, fmaxf(-30.f, x));
    return rcpf_(1.f + ex2(-x*1.4426950408889634f));
}

struct WPtrs {
    const float* w1[5]; const float* b1[5];
    const float* w2[5]; const float* b2[5];
};

// MLP 3->16->32->64->128->COUT, tanh between hidden layers, linear head.
// All register arrays statically indexed; weight addresses lane-uniform -> s_load.
template<int COUT>
DEV void run_mlp(const float* const* wp, const float* const* bp,
                 float x0, float x1, float x2, float* o){
    const float* w0=wp[0]; const float* w1=wp[1]; const float* w2=wp[2];
    const float* w3=wp[3]; const float* w4=wp[4];
    const float* b0=bp[0]; const float* b1=bp[1]; const float* b2=bp[2];
    const float* b3=bp[3]; const float* b4=bp[4];
    float h1[16];
#pragma unroll
    for (int j=0;j<16;++j)
        h1[j]=tanh_f(b0[j]+x0*w0[j]+x1*w0[16+j]+x2*w0[32+j]);
    float h2[32];
#pragma unroll
    for (int j=0;j<32;++j){
        float a=b1[j];
#pragma unroll
        for (int k=0;k<16;++k) a+=h1[k]*w1[k*32+j];
        h2[j]=tanh_f(a);
    }
    float h3[64];
#pragma unroll
    for (int j=0;j<64;++j){
        float a=b2[j];
#pragma unroll
        for (int k=0;k<32;++k) a+=h2[k]*w2[k*64+j];
        h3[j]=tanh_f(a);
    }
    float acc[COUT];
#pragma unroll
    for (int n=0;n<COUT;++n) acc[n]=b4[n];
    // fused layers 4+5: 64->128 (tanh) -> COUT, chunks of 8 hidden units
#pragma unroll 1
    for (int kc=0;kc<16;++kc){
        float t[8];
#pragma unroll
        for (int i=0;i<8;++i){
            float a=b3[kc*8+i];
#pragma unroll
            for (int k=0;k<64;++k) a+=h3[k]*w3[k*128+kc*8+i];
            t[i]=tanh_f(a);
        }
#pragma unroll
        for (int i=0;i<8;++i){
#pragma unroll
            for (int n=0;n<COUT;++n) acc[n]+=t[i]*w4[(kc*8+i)*COUT+n];
        }
    }
#pragma unroll
    for (int n=0;n<COUT;++n) o[n]=acc[n];
}

__global__ __launch_bounds__(256)
void dlut_kernel(const float* __restrict__ df, const float* __restrict__ lr,
                 WPtrs wp, float* __restrict__ out){
    constexpr int Hh=359, Ww=639, HW=Hh*Ww, NP=2*HW;
    constexpr int LHW=360*640;
    int p = blockIdx.x*blockDim.x + threadIdx.x;
    if (p>=NP) return;
    int b = p/HW; int r = p - b*HW;
    int h = r/Ww; int w = r - h*Ww;

    float x0=df[(b*3+0)*HW+r];
    float x1=df[(b*3+1)*HW+r];
    float x2=df[(b*3+2)*HW+r];

    // MLP2 -> s
    float sraw;
    run_mlp<1>(wp.w2, wp.b2, x0,x1,x2, &sraw);
    float s = sigm(sraw)+0.05f;

    // MLP1 -> F_r[64]
    float Fr[64];
    run_mlp<64>(wp.w1, wp.b1, x0,x1,x2, Fr);
#pragma unroll
    for (int n=0;n<64;++n) Fr[n]=sigm(Fr[n]);

    // Gaussian * Fr filters, double normalization
    float li = 0.72134752044f * rcpf_(s);   // log2(e)/(2s)
    float filt[4][16];
    float s16[4];
#pragma unroll
    for (int d=0;d<4;++d){
        float cy=1.25f+0.5f*(float)(d>>1), cx=1.25f+0.5f*(float)(d&1);
        float g[16]; float gs=0.f;
#pragma unroll
        for (int k=0;k<16;++k){
            float dy=(float)(k>>2)-cy, dx=(float)(k&3)-cx;
            float d2=dy*dy+dx*dx;                // compile-time constant
            g[k]=ex2(-d2*li);
            gs+=g[k];
        }
        float rg = rcpf_(gs+1e-12f);
        float fs=0.f;
#pragma unroll
        for (int k=0;k<16;++k){
            float f=g[k]*rg*Fr[d*16+k];
            filt[d][k]=f; fs+=f;
        }
        s16[d]=fs+1e-12f;
        float rf=rcpf_(s16[d]);
#pragma unroll
        for (int k=0;k<16;++k) filt[d][k]*=rf;
    }

    // 4x4 unfold of LR (pad=1), accumulate y[c][d]
    float y[3][4]={};
#pragma unroll
    for (int ky=0;ky<4;++ky){
        int yy=h+ky-1;
        int yyc = yy<0?0:(yy>359?359:yy);
        bool oky = (yy>=0)&&(yy<360);
#pragma unroll
        for (int kx=0;kx<4;++kx){
            int xx=w+kx-1;
            int xxc = xx<0?0:(xx>639?639:xx);
            bool ok = oky&&(xx>=0)&&(xx<640);
            int k=ky*4+kx;
            int base = (b*3)*LHW + yyc*640 + xxc;
#pragma unroll
            for (int c=0;c<3;++c){
                float pv = lr[base + c*LHW];
                pv = ok ? pv : 0.f;
#pragma unroll
                for (int d=0;d<4;++d) y[c][d]+=pv*filt[d][k];
            }
        }
    }

    // y_up: [B,3,2H,2W] f32; d = dy*2+dx -> pixel (2h+dy, 2w+dx); pack dx pair as float2
    float2* oy=(float2*)out;
#pragma unroll
    for (int c=0;c<3;++c){
#pragma unroll
        for (int dy=0;dy<2;++dy){
            float2 pk; pk.x=y[c][dy*2+0]; pk.y=y[c][dy*2+1];
            oy[((b*3+c)*718 + 2*h+dy)*639 + w] = pk;
        }
    }
    // sum16_out: [B,4,1,H,W] appended after y_up (5,505,624 floats)
    float* os = out + 5505624;
#pragma unroll
    for (int d=0;d<4;++d) os[((b*4+d)*359+h)*639+w]=s16[d];
}

extern "C" void kernel_launch(void* const* d_in, const int* in_sizes, int n_in,
                              void* d_out, int out_size, void* d_ws, size_t ws_size,
                              hipStream_t stream){
    const float* df=(const float*)d_in[0];
    const float* lr=(const float*)d_in[1];

    // dict order: for i in 0..4: m1_w i, m1_b i, m2_w i, m2_b i -> d_in[2+4i .. 5+4i]
    WPtrs wp;
    for (int i=0;i<5;++i){
        wp.w1[i]=(const float*)d_in[2+4*i];
        wp.b1[i]=(const float*)d_in[3+4*i];
        wp.w2[i]=(const float*)d_in[4+4*i];
        wp.b2[i]=(const float*)d_in[5+4*i];
    }

    int NP=2*359*639;
    hipLaunchKernelGGL(dlut_kernel, dim3((NP+255)/256), dim3(256), 0, stream,
                       df, lr, wp, (float*)d_out);
}

// Round 3
// 1106.245 us; speedup vs baseline: 1.0011x; 1.0011x over previous
//
#include <hip/hip_runtime.h>

typedef unsigned int u32;

#define DEV static __device__ __forceinline__

DEV float ex2(float x){ return __builtin_amdgcn_exp2f(x); }
DEV float rcpf_(float x){ return __builtin_amdgcn_rcpf(x); }

DEV float tanh_f(float x){
    x = fminf(12.f, fmaxf(-12.f, x));
    float t = ex2(x*2.885390082f);          // e^(2x) = 2^(2x*log2(e))
    return (t-1.f)*rcpf_(t+1.f);
}
DEV float sigm(float x){
    x = fminf(30.f, fmaxf(-30.f, x));
    return rcpf_(1.f + ex2(-x*1.4426950408889634f));
}

struct WPtrs {
    const float* w1[5]; const float* b1[5];
    const float* w2[5]; const float* b2[5];
};

// MLP 3->16->32->64->128->COUT, tanh between hidden layers, linear head.
// All register arrays statically indexed; weight addresses lane-uniform -> s_load.
template<int COUT>
DEV void run_mlp(const float* const* wp, const float* const* bp,
                 float x0, float x1, float x2, float* o){
    const float* w0=wp[0]; const float* w1=wp[1]; const float* w2=wp[2];
    const float* w3=wp[3]; const float* w4=wp[4];
    const float* b0=bp[0]; const float* b1=bp[1]; const float* b2=bp[2];
    const float* b3=bp[3]; const float* b4=bp[4];
    float h1[16];
#pragma unroll
    for (int j=0;j<16;++j)
        h1[j]=tanh_f(b0[j]+x0*w0[j]+x1*w0[16+j]+x2*w0[32+j]);
    float h2[32];
#pragma unroll
    for (int j=0;j<32;++j){
        float a=b1[j];
#pragma unroll
        for (int k=0;k<16;++k) a+=h1[k]*w1[k*32+j];
        h2[j]=tanh_f(a);
    }
    float h3[64];
#pragma unroll
    for (int j=0;j<64;++j){
        float a=b2[j];
#pragma unroll
        for (int k=0;k<32;++k) a+=h2[k]*w2[k*64+j];
        h3[j]=tanh_f(a);
    }
    float acc[COUT];
#pragma unroll
    for (int n=0;n<COUT;++n) acc[n]=b4[n];
    // fused layers 4+5: 64->128 (tanh) -> COUT, chunks of 8 hidden units
#pragma unroll 1
    for (int kc=0;kc<16;++kc){
        float t[8];
#pragma unroll
        for (int i=0;i<8;++i){
            float a=b3[kc*8+i];
#pragma unroll
            for (int k=0;k<64;++k) a+=h3[k]*w3[k*128+kc*8+i];
            t[i]=tanh_f(a);
        }
#pragma unroll
        for (int i=0;i<8;++i){
#pragma unroll
            for (int n=0;n<COUT;++n) acc[n]+=t[i]*w4[(kc*8+i)*COUT+n];
        }
    }
#pragma unroll
    for (int n=0;n<COUT;++n) o[n]=acc[n];
}

__global__ __launch_bounds__(256, 1)   // min 1 wave/EU: unlock full VGPR budget, no AGPR/scratch spill
void dlut_kernel(const float* __restrict__ df, const float* __restrict__ lr,
                 WPtrs wp, float* __restrict__ out){
    constexpr int Hh=359, Ww=639, HW=Hh*Ww, NP=2*HW;
    constexpr int LHW=360*640;
    int p = blockIdx.x*blockDim.x + threadIdx.x;
    if (p>=NP) return;
    int b = p/HW; int r = p - b*HW;
    int h = r/Ww; int w = r - h*Ww;

    float x0=df[(b*3+0)*HW+r];
    float x1=df[(b*3+1)*HW+r];
    float x2=df[(b*3+2)*HW+r];

    // MLP2 -> s  (COUT=1, low pressure; run first)
    float sraw;
    run_mlp<1>(wp.w2, wp.b2, x0,x1,x2, &sraw);
    float s = sigm(sraw)+0.05f;

    // MLP1 -> F_r[64]
    float Fr[64];
    run_mlp<64>(wp.w1, wp.b1, x0,x1,x2, Fr);
#pragma unroll
    for (int n=0;n<64;++n) Fr[n]=sigm(Fr[n]);

    // Preload 4x4 patch (pad=1, zero-fill) once: pv[c][k]
    float pv[3][16];
#pragma unroll
    for (int ky=0;ky<4;++ky){
        int yy=h+ky-1;
        int yyc = yy<0?0:(yy>359?359:yy);
        bool oky = (yy>=0)&&(yy<360);
#pragma unroll
        for (int kx=0;kx<4;++kx){
            int xx=w+kx-1;
            int xxc = xx<0?0:(xx>639?639:xx);
            bool ok = oky&&(xx>=0)&&(xx<640);
            int k=ky*4+kx;
            int base = (b*3)*LHW + yyc*640 + xxc;
#pragma unroll
            for (int c=0;c<3;++c){
                float v = lr[base + c*LHW];
                pv[c][k] = ok ? v : 0.f;
            }
        }
    }

    // Per-direction: Gaussian filter, double normalization, accumulate y
    float li = 0.72134752044f * rcpf_(s);   // log2(e)/(2s)
    float y[3][4];
    float s16[4];
#pragma unroll
    for (int d=0;d<4;++d){
        float cy=1.25f+0.5f*(float)(d>>1), cx=1.25f+0.5f*(float)(d&1);
        float g[16]; float gs=0.f;
#pragma unroll
        for (int k=0;k<16;++k){
            float dy=(float)(k>>2)-cy, dx=(float)(k&3)-cx;
            float d2=dy*dy+dx*dx;                // compile-time constant
            g[k]=ex2(-d2*li);
            gs+=g[k];
        }
        float rg = rcpf_(gs+1e-12f);
        float fs=0.f;
#pragma unroll
        for (int k=0;k<16;++k){
            float f=g[k]*rg*Fr[d*16+k];
            g[k]=f; fs+=f;
        }
        s16[d]=fs+1e-12f;
        float rf=rcpf_(s16[d]);
        float a0=0.f,a1=0.f,a2=0.f;
#pragma unroll
        for (int k=0;k<16;++k){
            float f=g[k]*rf;
            a0+=pv[0][k]*f; a1+=pv[1][k]*f; a2+=pv[2][k]*f;
        }
        y[0][d]=a0; y[1][d]=a1; y[2][d]=a2;
    }

    // y_up: [B,3,2H,2W] f32; d = dy*2+dx -> pixel (2h+dy, 2w+dx); pack dx pair as float2
    float2* oy=(float2*)out;
#pragma unroll
    for (int c=0;c<3;++c){
#pragma unroll
        for (int dy=0;dy<2;++dy){
            float2 pk; pk.x=y[c][dy*2+0]; pk.y=y[c][dy*2+1];
            oy[((b*3+c)*718 + 2*h+dy)*639 + w] = pk;
        }
    }
    // sum16_out: [B,4,1,H,W] appended after y_up (5,505,624 floats)
    float* os = out + 5505624;
#pragma unroll
    for (int d=0;d<4;++d) os[((b*4+d)*359+h)*639+w]=s16[d];
}

extern "C" void kernel_launch(void* const* d_in, const int* in_sizes, int n_in,
                              void* d_out, int out_size, void* d_ws, size_t ws_size,
                              hipStream_t stream){
    const float* df=(const float*)d_in[0];
    const float* lr=(const float*)d_in[1];

    // dict order: for i in 0..4: m1_w i, m1_b i, m2_w i, m2_b i -> d_in[2+4i .. 5+4i]
    WPtrs wp;
    for (int i=0;i<5;++i){
        wp.w1[i]=(const float*)d_in[2+4*i];
        wp.b1[i]=(const float*)d_in[3+4*i];
        wp.w2[i]=(const float*)d_in[4+4*i];
        wp.b2[i]=(const float*)d_in[5+4*i];
    }

    int NP=2*359*639;
    hipLaunchKernelGGL(dlut_kernel, dim3((NP+255)/256), dim3(256), 0, stream,
                       df, lr, wp, (float*)d_out);
}

// Round 4
// 248.489 us; speedup vs baseline: 4.4567x; 4.4519x over previous
//
#include <hip/hip_runtime.h>

typedef unsigned short u16;
typedef unsigned int u32;
typedef unsigned long long u64;
typedef short short8 __attribute__((ext_vector_type(8)));   // 8 bf16 (4 VGPRs)
typedef float f32x4 __attribute__((ext_vector_type(4)));

#define DEV static __device__ __forceinline__

DEV float ex2(float x){ return __builtin_amdgcn_exp2f(x); }
DEV float rcpf_(float x){ return __builtin_amdgcn_rcpf(x); }
DEV float bf2f(u16 v){ union {u32 u; float f;} c; c.u=((u32)v)<<16; return c.f; }
DEV u16 f2bf(float f){ union {u32 u; float f;} c; c.f=f; u32 r=c.u+0x7fffu+((c.u>>16)&1u); return (u16)(r>>16); }

DEV float tanh_f(float x){
    float xc = fminf(12.f, fmaxf(-12.f, x));
    float t = ex2(xc*2.885390082f);          // e^(2x)
    return 1.f - 2.f*rcpf_(t+1.f);
}
DEV float sigm(float x){
    float xc = fminf(30.f, fmaxf(-30.f, x));
    return rcpf_(1.f + ex2(-xc*1.4426950408889634f));
}

DEV short8 ld8(const u16* p){   // 8 consecutive u16 from LDS (8B-aligned) -> short8
    union { u64 q[2]; short8 v; } u;
    u.q[0] = *(const u64*)(p);
    u.q[1] = *(const u64*)(p+4);
    return u.v;
}
DEV f32x4 mfma16(short8 a, short8 b, f32x4 c){
    return __builtin_amdgcn_mfma_f32_16x16x32_bf16(a, b, c, 0, 0, 0);
}

// ---------------- weight prep: pack B-fragments (hi/lo bf16) + padded biases into d_ws
// ws layout: u16 hi[32768] | u16 lo[32768] | f32 bias[528]   (bias at float offset 32768)
// 8 MFMA layers l: M1L2,M1L3,M1L4,M1L5, M2L2,M2L3,M2L4,M2L5
// frag elem (kt,nt,lane,i): k=kt*32+(lane>>4)*8+i, n=nt*16+(lane&15); zero-padded
struct PrepArgs { const float* w[8]; const float* b[8]; };

__global__ void prep_kernel(PrepArgs pa, float* ws){
    u16* whi = (u16*)ws;
    u16* wlo = whi + 32768;
    float* bo = ws + 32768;
    const int K_[8]  = {16,32,64,128, 16,32,64,128};
    const int N_[8]  = {32,64,128,64, 32,64,128,1};
    const int NT_[8] = {2,4,8,4, 2,4,8,1};
    const int FB_[8] = {0,1024,3072,11264, 19456,20480,22528,30720};
    const int BB_[8] = {0,32,96,224, 288,320,384,512};
    int tid = blockIdx.x*256 + threadIdx.x;
    if (tid < 32768){
        int l = 0;
#pragma unroll
        for (int i=1;i<8;++i) if (tid >= FB_[i]) l = i;
        int idx = tid - FB_[l];
        int ktnt = idx >> 9;
        int nt = ktnt % NT_[l], kt = ktnt / NT_[l];
        int lane = (idx >> 3) & 63;
        int i = idx & 7;
        int k = kt*32 + ((lane>>4)<<3) + i;
        int n = nt*16 + (lane&15);
        const float* wsrc = pa.w[l];
        float v = (k < K_[l] && n < N_[l]) ? wsrc[k*N_[l] + n] : 0.f;
        u16 hi = f2bf(v);
        u16 lo = f2bf(v - bf2f(hi));
        whi[tid] = hi; wlo[tid] = lo;
    } else if (tid < 32768 + 528){
        int t = tid - 32768;
        int l = 0;
#pragma unroll
        for (int i=1;i<8;++i) if (t >= BB_[i]) l = i;
        int n = t - BB_[l];
        bo[t] = (n < N_[l]) ? pa.b[l][n] : 0.f;
    }
}

// ---------------- layer-1 (3->16) on VALU in f32, output split hi/lo bf16 to LDS
DEV void l1_valu(float x0,float x1,float x2, const float* w, const float* bias,
                 u16* outHi, u16* outLo, int lane){
    int pxl = lane & 31, jb = (lane>>5)*8;
#pragma unroll
    for (int j=0;j<8;++j){
        int jj = jb + j;
        float v = tanh_f(bias[jj] + x0*w[jj] + x1*w[16+jj] + x2*w[32+jj]);
        u16 hi = f2bf(v);
        u16 lo = f2bf(v - bf2f(hi));
        outHi[pxl*68 + jj] = hi;
        outLo[pxl*68 + jj] = lo;
    }
}

// ---------------- generic MFMA layer: 32px (2 mtiles) x [Kpad=KT*32 -> N=NT*16]
// A: row=lane&15, k=(lane>>4)*8+i ; B frag preloaded; C: col=lane&15, row=(lane>>4)*4+r
// hi/lo split on both sides, lo*lo dropped. ACT: 0=tanh, 1=sigmoid, 2=raw->sPre(col0)
template<int KT, int NT, int ACT>
DEV void layer(const u16* inHi, const u16* inLo, int inStr,
               u16* outHi, u16* outLo, int outStr,
               const u16* fHi, const u16* fLo, const float* bias,
               float* sPre, int lane){
    short8 ahi[2][KT], alo[2][KT];
    int rbase = lane & 15, koff = (lane>>4)<<3;
#pragma unroll
    for (int mt=0;mt<2;++mt)
#pragma unroll
    for (int kt=0;kt<KT;++kt){
        int off = (mt*16 + rbase)*inStr + kt*32 + koff;
        ahi[mt][kt] = ld8(inHi + off);
        alo[mt][kt] = ld8(inLo + off);
    }
#pragma unroll 2
    for (int nt=0; nt<NT; ++nt){
        f32x4 aA[2], aB[2], aC[2];
#pragma unroll
        for (int mt=0;mt<2;++mt){
            aA[mt]=(f32x4){0.f,0.f,0.f,0.f};
            aB[mt]=(f32x4){0.f,0.f,0.f,0.f};
            aC[mt]=(f32x4){0.f,0.f,0.f,0.f};
        }
#pragma unroll
        for (int kt=0;kt<KT;++kt){
            short8 bh = *(const short8*)(fHi + (((kt*NT+nt)<<6) + lane)*8);
            short8 bl = *(const short8*)(fLo + (((kt*NT+nt)<<6) + lane)*8);
#pragma unroll
            for (int mt=0;mt<2;++mt){
                aA[mt] = mfma16(ahi[mt][kt], bh, aA[mt]);
                aB[mt] = mfma16(ahi[mt][kt], bl, aB[mt]);
                aC[mt] = mfma16(alo[mt][kt], bh, aC[mt]);
            }
        }
        float bv = bias[nt*16 + rbase];
#pragma unroll
        for (int mt=0;mt<2;++mt){
#pragma unroll
            for (int r=0;r<4;++r){
                float v = aA[mt][r] + aB[mt][r] + aC[mt][r] + bv;
                int row = mt*16 + ((lane>>4)<<2) + r;
                if constexpr (ACT==2){
                    if (rbase==0) sPre[row] = v;
                } else {
                    if constexpr (ACT==0) v = tanh_f(v); else v = sigm(v);
                    u16 hi = f2bf(v);
                    u16 lo = f2bf(v - bf2f(hi));
                    outHi[row*outStr + nt*16 + rbase] = hi;
                    outLo[row*outStr + nt*16 + rbase] = lo;
                }
            }
        }
    }
}

__global__ __launch_bounds__(64, 2)
void dlut_kernel(const float* __restrict__ df, const float* __restrict__ lr,
                 const float* __restrict__ w1_0, const float* __restrict__ b1_0,
                 const float* __restrict__ w2_0, const float* __restrict__ b2_0,
                 const float* __restrict__ ws, float* __restrict__ out){
    constexpr int Hh=359, Ww=639, HW=Hh*Ww, NP=2*HW, LHW=360*640;
    __shared__ u16 sAh[32][68], sAl[32][68];     // <=64-ch activations (hi/lo)
    __shared__ u16 sBh[32][132], sBl[32][132];   // <=128-ch activations (hi/lo)
    __shared__ float sPre[32];

    const u16* whi = (const u16*)ws;
    const u16* wlo = whi + 32768;
    const float* bo = ws + 32768;

    int lane = threadIdx.x;
    int pxl = lane & 31, hv = lane >> 5;
    int px0 = blockIdx.x * 32;
    int p = px0 + pxl;

    // zero A-buf cols 16..31 (read by L2's K-pad; must not be NaN garbage)
    {
        u32* z0 = (u32*)&sAh[pxl][16 + hv*8];
        u32* z1 = (u32*)&sAl[pxl][16 + hv*8];
#pragma unroll
        for (int i=0;i<4;++i){ z0[i]=0u; z1[i]=0u; }
    }

    float x0=0.f, x1=0.f, x2=0.f;
    int b=0, r2=0, hh=0, wwp=0;
    if (p < NP){
        b = p/HW; r2 = p - b*HW; hh = r2/Ww; wwp = r2 - hh*Ww;
        x0 = df[(b*3+0)*HW + r2];
        x1 = df[(b*3+1)*HW + r2];
        x2 = df[(b*3+2)*HW + r2];
    }
    __syncthreads();

    // ===== MLP2 (scale head) =====
    l1_valu(x0,x1,x2, w2_0, b2_0, &sAh[0][0], &sAl[0][0], lane);
    __syncthreads();
    layer<1,2,0>(&sAh[0][0],&sAl[0][0],68,  &sBh[0][0],&sBl[0][0],132, whi+19456,wlo+19456, bo+288, sPre, lane);
    __syncthreads();
    layer<1,4,0>(&sBh[0][0],&sBl[0][0],132, &sAh[0][0],&sAl[0][0],68,  whi+20480,wlo+20480, bo+320, sPre, lane);
    __syncthreads();
    layer<2,8,0>(&sAh[0][0],&sAl[0][0],68,  &sBh[0][0],&sBl[0][0],132, whi+22528,wlo+22528, bo+384, sPre, lane);
    __syncthreads();
    layer<4,1,2>(&sBh[0][0],&sBl[0][0],132, (u16*)nullptr,(u16*)nullptr,0, whi+30720,wlo+30720, bo+512, sPre, lane);
    __syncthreads();
    // ===== MLP1 (F_r head) =====
    l1_valu(x0,x1,x2, w1_0, b1_0, &sAh[0][0], &sAl[0][0], lane);
    __syncthreads();
    layer<1,2,0>(&sAh[0][0],&sAl[0][0],68,  &sBh[0][0],&sBl[0][0],132, whi+0,    wlo+0,     bo+0,   sPre, lane);
    __syncthreads();
    layer<1,4,0>(&sBh[0][0],&sBl[0][0],132, &sAh[0][0],&sAl[0][0],68,  whi+1024, wlo+1024,  bo+32,  sPre, lane);
    __syncthreads();
    layer<2,8,0>(&sAh[0][0],&sAl[0][0],68,  &sBh[0][0],&sBl[0][0],132, whi+3072, wlo+3072,  bo+96,  sPre, lane);
    __syncthreads();
    layer<4,4,1>(&sBh[0][0],&sBl[0][0],132, &sAh[0][0],&sAl[0][0],68,  whi+11264,wlo+11264, bo+224, sPre, lane);
    __syncthreads();
    // Fr (sigmoid'd, hi/lo) now in sAh/sAl[px][0..63]; s pre-act in sPre[px]

    // ===== filters + unfold + writes: lane covers (px=lane&31, d in {hv*2, hv*2+1}) =====
    if (p < NP){
        float s = sigm(sPre[pxl]) + 0.05f;
        float li = 0.72134752044f * rcpf_(s);   // log2(e)/(2s)
        float pvv[3][16];
#pragma unroll
        for (int ky=0;ky<4;++ky){
            int yy=hh+ky-1;
            int yyc = yy<0?0:(yy>359?359:yy);
            bool oky = (yy>=0)&&(yy<360);
#pragma unroll
            for (int kx=0;kx<4;++kx){
                int xx=wwp+kx-1;
                int xxc = xx<0?0:(xx>639?639:xx);
                bool ok = oky&&(xx>=0)&&(xx<640);
                int k=ky*4+kx;
                int base = (b*3)*LHW + yyc*640 + xxc;
#pragma unroll
                for (int c=0;c<3;++c){
                    float v = lr[base + c*LHW];
                    pvv[c][k] = ok ? v : 0.f;
                }
            }
        }
#pragma unroll
        for (int dd=0; dd<2; ++dd){
            int d = hv*2 + dd;
            float cy=1.25f+0.5f*(float)(d>>1), cx=1.25f+0.5f*(float)(d&1);
            float g[16]; float gs=0.f;
#pragma unroll
            for (int k=0;k<16;++k){
                float dyv=(float)(k>>2)-cy, dxv=(float)(k&3)-cx;
                float d2=dyv*dyv+dxv*dxv;       // compile-time constant
                g[k]=ex2(-d2*li);
                gs+=g[k];
            }
            float rg = rcpf_(gs+1e-12f);
            float fs=0.f;
#pragma unroll
            for (int k=0;k<16;++k){
                float fr = bf2f(sAh[pxl][d*16+k]) + bf2f(sAl[pxl][d*16+k]);
                float f = g[k]*rg*fr;
                g[k]=f; fs+=f;
            }
            float s16v = fs + 1e-12f;
            float rf = rcpf_(s16v);
            float y0=0.f,y1=0.f,y2=0.f;
#pragma unroll
            for (int k=0;k<16;++k){
                float f = g[k]*rf;
                y0+=pvv[0][k]*f; y1+=pvv[1][k]*f; y2+=pvv[2][k]*f;
            }
            int dy=d>>1, dx=d&1;
            int rc = (2*hh+dy)*1278 + 2*wwp+dx;
            out[((b*3+0)*718)*1278 + rc] = y0;
            out[((b*3+1)*718)*1278 + rc] = y1;
            out[((b*3+2)*718)*1278 + rc] = y2;
            out[5505624 + ((b*4+d)*359 + hh)*639 + wwp] = s16v;
        }
    }
}

extern "C" void kernel_launch(void* const* d_in, const int* in_sizes, int n_in,
                              void* d_out, int out_size, void* d_ws, size_t ws_size,
                              hipStream_t stream){
    const float* df=(const float*)d_in[0];
    const float* lr=(const float*)d_in[1];
    // dict order per i: m1_w i -> d_in[2+4i], m1_b i -> [3+4i], m2_w i -> [4+4i], m2_b i -> [5+4i]
    PrepArgs pa;
    for (int i=0;i<4;++i){
        pa.w[i]   = (const float*)d_in[2+4*(i+1)];   // m1_w1..m1_w4
        pa.b[i]   = (const float*)d_in[3+4*(i+1)];   // m1_b1..m1_b4
        pa.w[4+i] = (const float*)d_in[4+4*(i+1)];   // m2_w1..m2_w4
        pa.b[4+i] = (const float*)d_in[5+4*(i+1)];   // m2_b1..m2_b4
    }
    float* ws = (float*)d_ws;
    hipLaunchKernelGGL(prep_kernel, dim3(131), dim3(256), 0, stream, pa, ws);

    constexpr int NP = 2*359*639;
    hipLaunchKernelGGL(dlut_kernel, dim3((NP+31)/32), dim3(64), 0, stream,
                       df, lr,
                       (const float*)d_in[2], (const float*)d_in[3],
                       (const float*)d_in[4], (const float*)d_in[5],
                       (const float*)ws, (float*)d_out);
}

// Round 5
// 125.170 us; speedup vs baseline: 8.8475x; 1.9852x over previous
//
#include <hip/hip_runtime.h>

typedef unsigned short u16;
typedef unsigned int u32;
typedef unsigned long long u64;
typedef short short8 __attribute__((ext_vector_type(8)));   // 8 bf16 (4 VGPRs)
typedef float f32x4 __attribute__((ext_vector_type(4)));

#define DEV static __device__ __forceinline__

DEV float ex2(float x){ return __builtin_amdgcn_exp2f(x); }
DEV float rcpf_(float x){ return __builtin_amdgcn_rcpf(x); }
DEV float bf2f(u16 v){ union {u32 u; float f;} c; c.u=((u32)v)<<16; return c.f; }
DEV u16 f2bf(float f){ union {u32 u; float f;} c; c.f=f; u32 r=c.u+0x7fffu+((c.u>>16)&1u); return (u16)(r>>16); }

DEV float tanh_f(float x){
    float xc = fminf(12.f, fmaxf(-12.f, x));
    float t = ex2(xc*2.885390082f);          // e^(2x)
    return 1.f - 2.f*rcpf_(t+1.f);
}
DEV float sigm(float x){
    float xc = fminf(30.f, fmaxf(-30.f, x));
    return rcpf_(1.f + ex2(-xc*1.4426950408889634f));
}

DEV short8 ld8(const u16* p){   // 8 consecutive u16 from LDS (8B-aligned) -> short8
    union { u64 q[2]; short8 v; } u;
    u.q[0] = *(const u64*)(p);
    u.q[1] = *(const u64*)(p+4);
    return u.v;
}
DEV f32x4 mfma16(short8 a, short8 b, f32x4 c){
    return __builtin_amdgcn_mfma_f32_16x16x32_bf16(a, b, c, 0, 0, 0);
}

// ---------------- weight prep: pack B-fragments (bf16) + padded biases into d_ws
// ws layout: u16 hi[32768] | f32 bias[528]  (bias at float offset 16384)
// 8 MFMA layers l: M1L2,M1L3,M1L4,M1L5, M2L2,M2L3,M2L4,M2L5
// frag elem (kt,nt,lane,i): k=kt*32+(lane>>4)*8+i, n=nt*16+(lane&15); zero-padded
struct PrepArgs { const float* w[8]; const float* b[8]; };

__global__ void prep_kernel(PrepArgs pa, float* ws){
    u16* whi = (u16*)ws;
    float* bo = ws + 16384;
    const int K_[8]  = {16,32,64,128, 16,32,64,128};
    const int N_[8]  = {32,64,128,64, 32,64,128,1};
    const int NT_[8] = {2,4,8,4, 2,4,8,1};
    const int FB_[8] = {0,1024,3072,11264, 19456,20480,22528,30720};
    const int BB_[8] = {0,32,96,224, 288,320,384,512};
    int tid = blockIdx.x*256 + threadIdx.x;
    if (tid < 32768){
        int l = 0;
#pragma unroll
        for (int i=1;i<8;++i) if (tid >= FB_[i]) l = i;
        int idx = tid - FB_[l];
        int ktnt = idx >> 9;
        int nt = ktnt % NT_[l], kt = ktnt / NT_[l];
        int lane = (idx >> 3) & 63;
        int i = idx & 7;
        int k = kt*32 + ((lane>>4)<<3) + i;
        int n = nt*16 + (lane&15);
        const float* wsrc = pa.w[l];
        float v = (k < K_[l] && n < N_[l]) ? wsrc[k*N_[l] + n] : 0.f;
        whi[tid] = f2bf(v);
    } else if (tid < 32768 + 528){
        int t = tid - 32768;
        int l = 0;
#pragma unroll
        for (int i=1;i<8;++i) if (t >= BB_[i]) l = i;
        int n = t - BB_[l];
        bo[t] = (n < N_[l]) ? pa.b[l][n] : 0.f;
    }
}

// ---------------- layer-1 (3->16) on VALU in f32, output bf16 to LDS
DEV void l1_valu(float x0,float x1,float x2, const float* w, const float* bias,
                 u16* outA, int lane){
    int pxl = lane & 31, jb = (lane>>5)*8;
#pragma unroll
    for (int j=0;j<8;++j){
        int jj = jb + j;
        float v = tanh_f(bias[jj] + x0*w[jj] + x1*w[16+jj] + x2*w[32+jj]);
        outA[pxl*68 + jj] = f2bf(v);
    }
}

// ---------------- generic MFMA layer: 32px (2 mtiles) x [Kpad=KT*32 -> N=NT*16]
// A: row=lane&15, k=(lane>>4)*8+i ; B frag preloaded; C: col=lane&15, row=(lane>>4)*4+r
// ACT: 0=tanh, 1=sigmoid, 2=raw->sPre (col 0 only)
template<int KT, int NT, int ACT>
DEV void layer(const u16* in, int inStr, u16* out, int outStr,
               const u16* fHi, const float* bias, float* sPre, int lane){
    short8 a[2][KT];
    int rbase = lane & 15, koff = (lane>>4)<<3;
#pragma unroll
    for (int mt=0;mt<2;++mt)
#pragma unroll
    for (int kt=0;kt<KT;++kt)
        a[mt][kt] = ld8(in + (mt*16 + rbase)*inStr + kt*32 + koff);
#pragma unroll 2
    for (int nt=0; nt<NT; ++nt){
        f32x4 acc[2];
#pragma unroll
        for (int mt=0;mt<2;++mt) acc[mt]=(f32x4){0.f,0.f,0.f,0.f};
#pragma unroll
        for (int kt=0;kt<KT;++kt){
            short8 bh = *(const short8*)(fHi + (((kt*NT+nt)<<6) + lane)*8);
#pragma unroll
            for (int mt=0;mt<2;++mt) acc[mt] = mfma16(a[mt][kt], bh, acc[mt]);
        }
        float bv = bias[nt*16 + rbase];
#pragma unroll
        for (int mt=0;mt<2;++mt){
#pragma unroll
            for (int r=0;r<4;++r){
                float v = acc[mt][r] + bv;
                int row = mt*16 + ((lane>>4)<<2) + r;
                if constexpr (ACT==2){
                    if (rbase==0) sPre[row] = v;
                } else {
                    if constexpr (ACT==0) v = tanh_f(v); else v = sigm(v);
                    out[row*outStr + nt*16 + rbase] = f2bf(v);
                }
            }
        }
    }
}

__global__ __launch_bounds__(64, 3)
void dlut_kernel(const float* __restrict__ df, const float* __restrict__ lr,
                 const float* __restrict__ w1_0, const float* __restrict__ b1_0,
                 const float* __restrict__ w2_0, const float* __restrict__ b2_0,
                 const float* __restrict__ ws, float* __restrict__ out){
    constexpr int Hh=359, Ww=639, HW=Hh*Ww, NP=2*HW, LHW=360*640;
    __shared__ u16 sA[32][68];     // <=64-ch activations
    __shared__ u16 sB[32][132];    // <=128-ch activations
    __shared__ float sPre[32];

    const u16* whi = (const u16*)ws;
    const float* bo = ws + 16384;

    int lane = threadIdx.x;
    int pxl = lane & 31, hv = lane >> 5;
    int px0 = blockIdx.x * 32;
    int p = px0 + pxl;

    // zero A-buf cols 16..31 once (layer-2 K-pad region: weights there are 0,
    // but uninitialized LDS could hold NaN bit patterns and NaN*0=NaN)
    {
        u32* z0 = (u32*)&sA[pxl][16 + hv*8];
#pragma unroll
        for (int i=0;i<4;++i) z0[i]=0u;
    }

    float x0=0.f, x1=0.f, x2=0.f;
    int b=0, r2=0, hh=0, wwp=0;
    if (p < NP){
        b = p/HW; r2 = p - b*HW; hh = r2/Ww; wwp = r2 - hh*Ww;
        x0 = df[(b*3+0)*HW + r2];
        x1 = df[(b*3+1)*HW + r2];
        x2 = df[(b*3+2)*HW + r2];
    }
    __syncthreads();

    // ===== MLP2 (scale head) =====
    l1_valu(x0,x1,x2, w2_0, b2_0, &sA[0][0], lane);
    __syncthreads();
    layer<1,2,0>(&sA[0][0],68,  &sB[0][0],132, whi+19456, bo+288, sPre, lane);
    __syncthreads();
    layer<1,4,0>(&sB[0][0],132, &sA[0][0],68,  whi+20480, bo+320, sPre, lane);
    __syncthreads();
    layer<2,8,0>(&sA[0][0],68,  &sB[0][0],132, whi+22528, bo+384, sPre, lane);
    __syncthreads();
    layer<4,1,2>(&sB[0][0],132, (u16*)nullptr,0, whi+30720, bo+512, sPre, lane);
    __syncthreads();
    // ===== MLP1 (F_r head) =====
    l1_valu(x0,x1,x2, w1_0, b1_0, &sA[0][0], lane);
    __syncthreads();
    layer<1,2,0>(&sA[0][0],68,  &sB[0][0],132, whi+0,     bo+0,   sPre, lane);
    __syncthreads();
    layer<1,4,0>(&sB[0][0],132, &sA[0][0],68,  whi+1024,  bo+32,  sPre, lane);
    __syncthreads();
    layer<2,8,0>(&sA[0][0],68,  &sB[0][0],132, whi+3072,  bo+96,  sPre, lane);
    __syncthreads();
    layer<4,4,1>(&sB[0][0],132, &sA[0][0],68,  whi+11264, bo+224, sPre, lane);
    __syncthreads();
    // Fr (sigmoid'd bf16) now in sA[px][0..63]; s pre-act in sPre[px]

    // ===== filters + unfold + writes: lane covers (px=lane&31, d in {hv*2, hv*2+1}) =====
    if (p < NP){
        float s = sigm(sPre[pxl]) + 0.05f;
        float li = 0.72134752044f * rcpf_(s);   // log2(e)/(2s)
        float pvv[3][16];
#pragma unroll
        for (int ky=0;ky<4;++ky){
            int yy=hh+ky-1;
            int yyc = yy<0?0:(yy>359?359:yy);
            bool oky = (yy>=0)&&(yy<360);
#pragma unroll
            for (int kx=0;kx<4;++kx){
                int xx=wwp+kx-1;
                int xxc = xx<0?0:(xx>639?639:xx);
                bool ok = oky&&(xx>=0)&&(xx<640);
                int k=ky*4+kx;
                int base = (b*3)*LHW + yyc*640 + xxc;
#pragma unroll
                for (int c=0;c<3;++c){
                    float v = lr[base + c*LHW];
                    pvv[c][k] = ok ? v : 0.f;
                }
            }
        }
#pragma unroll
        for (int dd=0; dd<2; ++dd){
            int d = hv*2 + dd;
            float cy=1.25f+0.5f*(float)(d>>1), cx=1.25f+0.5f*(float)(d&1);
            float g[16]; float gs=0.f;
#pragma unroll
            for (int k=0;k<16;++k){
                float dyv=(float)(k>>2)-cy, dxv=(float)(k&3)-cx;
                float d2=dyv*dyv+dxv*dxv;       // compile-time constant
                g[k]=ex2(-d2*li);
                gs+=g[k];
            }
            float rg = rcpf_(gs+1e-12f);
            float fs=0.f;
#pragma unroll
            for (int k=0;k<16;++k){
                float fr = bf2f(sA[pxl][d*16+k]);
                float f = g[k]*rg*fr;
                g[k]=f; fs+=f;
            }
            float s16v = fs + 1e-12f;
            float rf = rcpf_(s16v);
            float y0=0.f,y1=0.f,y2=0.f;
#pragma unroll
            for (int k=0;k<16;++k){
                float f = g[k]*rf;
                y0+=pvv[0][k]*f; y1+=pvv[1][k]*f; y2+=pvv[2][k]*f;
            }
            int dy=d>>1, dx=d&1;
            int rc = (2*hh+dy)*1278 + 2*wwp+dx;
            out[((b*3+0)*718)*1278 + rc] = y0;
            out[((b*3+1)*718)*1278 + rc] = y1;
            out[((b*3+2)*718)*1278 + rc] = y2;
            out[5505624 + ((b*4+d)*359 + hh)*639 + wwp] = s16v;
        }
    }
}

extern "C" void kernel_launch(void* const* d_in, const int* in_sizes, int n_in,
                              void* d_out, int out_size, void* d_ws, size_t ws_size,
                              hipStream_t stream){
    const float* df=(const float*)d_in[0];
    const float* lr=(const float*)d_in[1];
    // dict order per i: m1_w i -> d_in[2+4i], m1_b i -> [3+4i], m2_w i -> [4+4i], m2_b i -> [5+4i]
    PrepArgs pa;
    for (int i=0;i<4;++i){
        pa.w[i]   = (const float*)d_in[2+4*(i+1)];   // m1_w1..m1_w4
        pa.b[i]   = (const float*)d_in[3+4*(i+1)];   // m1_b1..m1_b4
        pa.w[4+i] = (const float*)d_in[4+4*(i+1)];   // m2_w1..m2_w4
        pa.b[4+i] = (const float*)d_in[5+4*(i+1)];   // m2_b1..m2_b4
    }
    float* ws = (float*)d_ws;
    hipLaunchKernelGGL(prep_kernel, dim3(131), dim3(256), 0, stream, pa, ws);

    constexpr int NP = 2*359*639;
    hipLaunchKernelGGL(dlut_kernel, dim3((NP+31)/32), dim3(64), 0, stream,
                       df, lr,
                       (const float*)d_in[2], (const float*)d_in[3],
                       (const float*)d_in[4], (const float*)d_in[5],
                       (const float*)ws, (float*)d_out);
}

// Round 6
// 112.295 us; speedup vs baseline: 9.8618x; 1.1146x over previous
//
#include <hip/hip_runtime.h>

typedef unsigned short u16;
typedef unsigned int u32;
typedef unsigned long long u64;
typedef short short8 __attribute__((ext_vector_type(8)));   // 8 bf16 (4 VGPRs)
typedef float f32x4 __attribute__((ext_vector_type(4)));

#define DEV static __device__ __forceinline__

DEV float ex2(float x){ return __builtin_amdgcn_exp2f(x); }
DEV float rcpf_(float x){ return __builtin_amdgcn_rcpf(x); }
DEV float bf2f(u16 v){ union {u32 u; float f;} c; c.u=((u32)v)<<16; return c.f; }
DEV u16 f2bf(float f){ union {u32 u; float f;} c; c.f=f; u32 r=c.u+0x7fffu+((c.u>>16)&1u); return (u16)(r>>16); }

// clampless: ex2(+-inf) saturates, rcp(inf)=0 -> correct +-1 / 0/1 limits, no NaN for finite x
DEV float tanh_f(float x){
    float t = ex2(x*2.885390082f);           // e^(2x)
    return 1.f - 2.f*rcpf_(t+1.f);
}
DEV float sigm(float x){
    return rcpf_(1.f + ex2(-x*1.4426950408889634f));
}
DEV u32 cvtpk(float lo, float hi){           // u32 = bf16(hi)<<16 | bf16(lo), RNE
    u32 r;
    asm("v_cvt_pk_bf16_f32 %0, %1, %2" : "=v"(r) : "v"(lo), "v"(hi));
    return r;
}

DEV short8 ld8(const u16* p){   // 8 consecutive u16 from LDS (8B-aligned) -> short8
    union { u64 q[2]; short8 v; } u;
    u.q[0] = *(const u64*)(p);
    u.q[1] = *(const u64*)(p+4);
    return u.v;
}
DEV f32x4 mfma16(short8 a, short8 b, f32x4 c){
    return __builtin_amdgcn_mfma_f32_16x16x32_bf16(a, b, c, 0, 0, 0);
}

// ---------------- weight prep: pack fragments (bf16) + padded biases into d_ws
// ws layout: u16 frag[32768] | f32 bias[528]  (bias at float offset 16384)
// 8 MFMA layers l: M1L2,M1L3,M1L4,M1L5, M2L2,M2L3,M2L4,M2L5
// frag elem (kt,ct,lane,i): k=kt*32+(lane>>4)*8+i, n=ct*16+(lane&15); zero-padded
// (identical A/B fragment index formula -> same packing serves W-as-A operand)
struct PrepArgs { const float* w[8]; const float* b[8]; };

__global__ void prep_kernel(PrepArgs pa, float* ws){
    u16* whi = (u16*)ws;
    float* bo = ws + 16384;
    const int K_[8]  = {16,32,64,128, 16,32,64,128};
    const int N_[8]  = {32,64,128,64, 32,64,128,1};
    const int NT_[8] = {2,4,8,4, 2,4,8,1};
    const int FB_[8] = {0,1024,3072,11264, 19456,20480,22528,30720};
    const int BB_[8] = {0,32,96,224, 288,320,384,512};
    int tid = blockIdx.x*256 + threadIdx.x;
    if (tid < 32768){
        int l = 0;
#pragma unroll
        for (int i=1;i<8;++i) if (tid >= FB_[i]) l = i;
        int idx = tid - FB_[l];
        int ktnt = idx >> 9;
        int nt = ktnt % NT_[l], kt = ktnt / NT_[l];
        int lane = (idx >> 3) & 63;
        int i = idx & 7;
        int k = kt*32 + ((lane>>4)<<3) + i;
        int n = nt*16 + (lane&15);
        const float* wsrc = pa.w[l];
        float v = (k < K_[l] && n < N_[l]) ? wsrc[k*N_[l] + n] : 0.f;
        whi[tid] = f2bf(v);
    } else if (tid < 32768 + 528){
        int t = tid - 32768;
        int l = 0;
#pragma unroll
        for (int i=1;i<8;++i) if (t >= BB_[i]) l = i;
        int n = t - BB_[l];
        bo[t] = (n < N_[l]) ? pa.b[l][n] : 0.f;
    }
}

// ---------------- layer-1 (3->16) on VALU in f32, packed bf16 stores
DEV void l1_valu(float x0,float x1,float x2, const float* w, const float* bias,
                 u16* outA, int lane){
    int pxl = lane & 31, jb = (lane>>5)*8;
    float v[8];
#pragma unroll
    for (int j=0;j<8;++j){
        int jj = jb + j;
        v[j] = tanh_f(bias[jj] + x0*w[jj] + x1*w[16+jj] + x2*w[32+jj]);
    }
    union { u32 d[2]; u64 q; } q0, q1;
    q0.d[0]=cvtpk(v[0],v[1]); q0.d[1]=cvtpk(v[2],v[3]);
    q1.d[0]=cvtpk(v[4],v[5]); q1.d[1]=cvtpk(v[6],v[7]);
    *(u64*)(outA + pxl*68 + jb)     = q0.q;
    *(u64*)(outA + pxl*68 + jb + 4) = q1.q;
}

// ---------------- swapped MFMA layer: D = mfma(W, X)
// A=weights: row=out-channel n=lane&15(+ct*16), k=(lane>>4)*8+i
// B=activations: col=pixel=lane&15(+pt*16), k=(lane>>4)*8+i  (ld8 from [px][ch] LDS)
// D: col=pixel=lane&15, row=out-channel=(lane>>4)*4+r (+ct*16)
//    -> 4 consecutive channels per lane: cvt_pk x2 + one ds_write_b64
// ACT: 0=tanh, 1=sigmoid, 2=raw channel0 -> sPre[px]
template<int KT, int CT, int ACT>
DEV void layer(const u16* in, int inStr, u16* out, int outStr,
               const u16* wf, const float* bias, float* sPre, int lane){
    short8 x[2][KT];
    int col = lane & 15, koff = (lane>>4)<<3;
#pragma unroll
    for (int pt=0;pt<2;++pt)
#pragma unroll
    for (int kt=0;kt<KT;++kt)
        x[pt][kt] = ld8(in + (pt*16 + col)*inStr + kt*32 + koff);
#pragma unroll 2
    for (int ct=0; ct<CT; ++ct){
        f32x4 acc[2];
        acc[0]=(f32x4){0.f,0.f,0.f,0.f};
        acc[1]=(f32x4){0.f,0.f,0.f,0.f};
#pragma unroll
        for (int kt=0;kt<KT;++kt){
            short8 wv = *(const short8*)(wf + (((kt*CT+ct)<<6) + lane)*8);
#pragma unroll
            for (int pt=0;pt<2;++pt) acc[pt] = mfma16(wv, x[pt][kt], acc[pt]);
        }
        if constexpr (ACT==2){
            // only channel 0 real (row 0 -> lanes 0..15, r=0)
            float v0 = acc[0][0] + bias[0];
            float v1 = acc[1][0] + bias[0];
            if ((lane>>4)==0){ sPre[col]=v0; sPre[16+col]=v1; }
        } else {
            int chb = ct*16 + ((lane>>4)<<2);
            float4 bv = *(const float4*)(bias + chb);
#pragma unroll
            for (int pt=0;pt<2;++pt){
                float v0 = acc[pt][0] + bv.x;
                float v1 = acc[pt][1] + bv.y;
                float v2 = acc[pt][2] + bv.z;
                float v3 = acc[pt][3] + bv.w;
                if constexpr (ACT==0){
                    v0=tanh_f(v0); v1=tanh_f(v1); v2=tanh_f(v2); v3=tanh_f(v3);
                } else {
                    v0=sigm(v0); v1=sigm(v1); v2=sigm(v2); v3=sigm(v3);
                }
                union { u32 d[2]; u64 q; } qq;
                qq.d[0]=cvtpk(v0,v1); qq.d[1]=cvtpk(v2,v3);
                *(u64*)(out + (pt*16 + col)*outStr + chb) = qq.q;
            }
        }
    }
}

__global__ __launch_bounds__(64, 3)
void dlut_kernel(const float* __restrict__ df, const float* __restrict__ lr,
                 const float* __restrict__ w1_0, const float* __restrict__ b1_0,
                 const float* __restrict__ w2_0, const float* __restrict__ b2_0,
                 const float* __restrict__ ws, float* __restrict__ out){
    constexpr int Hh=359, Ww=639, HW=Hh*Ww, NP=2*HW, LHW=360*640;
    __shared__ u16 sA[32][68];     // <=64-ch activations
    __shared__ u16 sB[32][132];    // <=128-ch activations
    __shared__ float sPre[32];

    const u16* whi = (const u16*)ws;
    const float* bo = ws + 16384;

    int lane = threadIdx.x;
    int pxl = lane & 31, hv = lane >> 5;
    int px0 = blockIdx.x * 32;
    int p = px0 + pxl;

    // zero A-buf cols 16..31 once (layer-2 K-pad region: weights there are 0,
    // but uninitialized LDS could hold NaN bit patterns and NaN*0=NaN)
    {
        u32* z0 = (u32*)&sA[pxl][16 + hv*8];
#pragma unroll
        for (int i=0;i<4;++i) z0[i]=0u;
    }

    float x0=0.f, x1=0.f, x2=0.f;
    int b=0, r2=0, hh=0, wwp=0;
    if (p < NP){
        b = p/HW; r2 = p - b*HW; hh = r2/Ww; wwp = r2 - hh*Ww;
        x0 = df[(b*3+0)*HW + r2];
        x1 = df[(b*3+1)*HW + r2];
        x2 = df[(b*3+2)*HW + r2];
    }
    __syncthreads();

    // ===== MLP2 (scale head) =====
    l1_valu(x0,x1,x2, w2_0, b2_0, &sA[0][0], lane);
    __syncthreads();
    layer<1,2,0>(&sA[0][0],68,  &sB[0][0],132, whi+19456, bo+288, sPre, lane);
    __syncthreads();
    layer<1,4,0>(&sB[0][0],132, &sA[0][0],68,  whi+20480, bo+320, sPre, lane);
    __syncthreads();
    layer<2,8,0>(&sA[0][0],68,  &sB[0][0],132, whi+22528, bo+384, sPre, lane);
    __syncthreads();
    layer<4,1,2>(&sB[0][0],132, (u16*)nullptr,0, whi+30720, bo+512, sPre, lane);
    __syncthreads();
    // ===== MLP1 (F_r head) =====
    l1_valu(x0,x1,x2, w1_0, b1_0, &sA[0][0], lane);
    __syncthreads();
    layer<1,2,0>(&sA[0][0],68,  &sB[0][0],132, whi+0,     bo+0,   sPre, lane);
    __syncthreads();
    layer<1,4,0>(&sB[0][0],132, &sA[0][0],68,  whi+1024,  bo+32,  sPre, lane);
    __syncthreads();
    layer<2,8,0>(&sA[0][0],68,  &sB[0][0],132, whi+3072,  bo+96,  sPre, lane);
    __syncthreads();
    layer<4,4,1>(&sB[0][0],132, &sA[0][0],68,  whi+11264, bo+224, sPre, lane);
    __syncthreads();
    // Fr (sigmoid'd bf16) now in sA[px][0..63]; s pre-act in sPre[px]

    // ===== filters + unfold + writes: lane covers (px=lane&31, d in {hv*2, hv*2+1}) =====
    if (p < NP){
        float s = sigm(sPre[pxl]) + 0.05f;
        float li = 0.72134752044f * rcpf_(s);   // log2(e)/(2s)
        float pvv[3][16];
#pragma unroll
        for (int ky=0;ky<4;++ky){
            int yy=hh+ky-1;
            int yyc = yy<0?0:(yy>359?359:yy);
            bool oky = (yy>=0)&&(yy<360);
#pragma unroll
            for (int kx=0;kx<4;++kx){
                int xx=wwp+kx-1;
                int xxc = xx<0?0:(xx>639?639:xx);
                bool ok = oky&&(xx>=0)&&(xx<640);
                int k=ky*4+kx;
                int base = (b*3)*LHW + yyc*640 + xxc;
#pragma unroll
                for (int c=0;c<3;++c){
                    float v = lr[base + c*LHW];
                    pvv[c][k] = ok ? v : 0.f;
                }
            }
        }
#pragma unroll
        for (int dd=0; dd<2; ++dd){
            int d = hv*2 + dd;
            float cy=1.25f+0.5f*(float)(d>>1), cx=1.25f+0.5f*(float)(d&1);
            float g[16]; float gs=0.f;
#pragma unroll
            for (int k=0;k<16;++k){
                float dyv=(float)(k>>2)-cy, dxv=(float)(k&3)-cx;
                float d2=dyv*dyv+dxv*dxv;       // compile-time constant
                g[k]=ex2(-d2*li);
                gs+=g[k];
            }
            float rg = rcpf_(gs+1e-12f);
            float fs=0.f;
#pragma unroll
            for (int k=0;k<16;++k){
                float fr = bf2f(sA[pxl][d*16+k]);
                float f = g[k]*rg*fr;
                g[k]=f; fs+=f;
            }
            float s16v = fs + 1e-12f;
            float rf = rcpf_(s16v);
            float y0=0.f,y1=0.f,y2=0.f;
#pragma unroll
            for (int k=0;k<16;++k){
                float f = g[k]*rf;
                y0+=pvv[0][k]*f; y1+=pvv[1][k]*f; y2+=pvv[2][k]*f;
            }
            int dy=d>>1, dx=d&1;
            int rc = (2*hh+dy)*1278 + 2*wwp+dx;
            out[((b*3+0)*718)*1278 + rc] = y0;
            out[((b*3+1)*718)*1278 + rc] = y1;
            out[((b*3+2)*718)*1278 + rc] = y2;
            out[5505624 + ((b*4+d)*359 + hh)*639 + wwp] = s16v;
        }
    }
}

extern "C" void kernel_launch(void* const* d_in, const int* in_sizes, int n_in,
                              void* d_out, int out_size, void* d_ws, size_t ws_size,
                              hipStream_t stream){
    const float* df=(const float*)d_in[0];
    const float* lr=(const float*)d_in[1];
    // dict order per i: m1_w i -> d_in[2+4i], m1_b i -> [3+4i], m2_w i -> [4+4i], m2_b i -> [5+4i]
    PrepArgs pa;
    for (int i=0;i<4;++i){
        pa.w[i]   = (const float*)d_in[2+4*(i+1)];   // m1_w1..m1_w4
        pa.b[i]   = (const float*)d_in[3+4*(i+1)];   // m1_b1..m1_b4
        pa.w[4+i] = (const float*)d_in[4+4*(i+1)];   // m2_w1..m2_w4
        pa.b[4+i] = (const float*)d_in[5+4*(i+1)];   // m2_b1..m2_b4
    }
    float* ws = (float*)d_ws;
    hipLaunchKernelGGL(prep_kernel, dim3(131), dim3(256), 0, stream, pa, ws);

    constexpr int NP = 2*359*639;
    hipLaunchKernelGGL(dlut_kernel, dim3((NP+31)/32), dim3(64), 0, stream,
                       df, lr,
                       (const float*)d_in[2], (const float*)d_in[3],
                       (const float*)d_in[4], (const float*)d_in[5],
                       (const float*)ws, (float*)d_out);
}

// Round 7
// 94.033 us; speedup vs baseline: 11.7772x; 1.1942x over previous
//
#include <hip/hip_runtime.h>

typedef unsigned short u16;
typedef unsigned int u32;
typedef unsigned long long u64;
typedef short short8 __attribute__((ext_vector_type(8)));   // 8 bf16 (4 VGPRs)
typedef float f32x4 __attribute__((ext_vector_type(4)));

#define DEV static __device__ __forceinline__

DEV float ex2(float x){ return __builtin_amdgcn_exp2f(x); }
DEV float rcpf_(float x){ return __builtin_amdgcn_rcpf(x); }
DEV float bf2f(u16 v){ union {u32 u; float f;} c; c.u=((u32)v)<<16; return c.f; }
DEV u16 f2bf(float f){ union {u32 u; float f;} c; c.f=f; u32 r=c.u+0x7fffu+((c.u>>16)&1u); return (u16)(r>>16); }

// prescaled activations: weights/biases already carry the log2e factors
DEV float tanh_ps(float v){          // v = 2*log2e*z ; tanh(z) = 1 - 2/(2^v+1)
    float t = ex2(v);
    return 1.f - 2.f*rcpf_(t+1.f);
}
DEV float sigm_ps(float v){          // v = -log2e*z ; sigma(z) = 1/(1+2^v)
    return rcpf_(1.f + ex2(v));
}
DEV u32 cvtpk(float lo, float hi){   // u32 = bf16(hi)<<16 | bf16(lo), RNE
    u32 r;
    asm("v_cvt_pk_bf16_f32 %0, %1, %2" : "=v"(r) : "v"(lo), "v"(hi));
    return r;
}
DEV short8 ld8(const u16* p){        // 8 consecutive u16 from LDS (8B-aligned)
    union { u64 q[2]; short8 v; } u;
    u.q[0] = *(const u64*)(p);
    u.q[1] = *(const u64*)(p+4);
    return u.v;
}
DEV f32x4 mfma16(short8 a, short8 b, f32x4 c){
    return __builtin_amdgcn_mfma_f32_16x16x32_bf16(a, b, c, 0, 0, 0);
}

// ---------------- weight prep: pack PRESCALED fragments + biases into d_ws
// ws layout: u16 frag[32768] | f32 bias[528] @16384 | f32 l1 m1_w48,m1_b16,m2_w48,m2_b16 @16912..17039
// 8 MFMA layers l: M1L2,M1L3,M1L4,M1L5, M2L2,M2L3,M2L4,M2L5
// frag elem (kt,ct,lane,i): k=kt*32+(lane>>4)*8+i, n=ct*16+(lane&15); zero-padded
struct PrepArgs { const float* w[8]; const float* b[8]; const float* l1w[2]; const float* l1b[2]; };

__global__ void prep_kernel(PrepArgs pa, float* ws){
    u16* whi = (u16*)ws;
    float* bo = ws + 16384;
    const int K_[8]  = {16,32,64,128, 16,32,64,128};
    const int N_[8]  = {32,64,128,64, 32,64,128,1};
    const int NT_[8] = {2,4,8,4, 2,4,8,1};
    const int FB_[8] = {0,1024,3072,11264, 19456,20480,22528,30720};
    const int BB_[8] = {0,32,96,224, 288,320,384,512};
    const float CT_ = 2.8853900817779268f;    // 2*log2(e)  (tanh layers)
    const float CS_ = -1.4426950408889634f;   // -log2(e)   (sigmoid heads)
    const float SC_[8] = {CT_,CT_,CT_,CS_, CT_,CT_,CT_,CS_};
    int tid = blockIdx.x*256 + threadIdx.x;
    if (tid < 32768){
        int l = 0;
#pragma unroll
        for (int i=1;i<8;++i) if (tid >= FB_[i]) l = i;
        int idx = tid - FB_[l];
        int ktnt = idx >> 9;
        int nt = ktnt % NT_[l], kt = ktnt / NT_[l];
        int lane = (idx >> 3) & 63;
        int i = idx & 7;
        int k = kt*32 + ((lane>>4)<<3) + i;
        int n = nt*16 + (lane&15);
        const float* wsrc = pa.w[l];
        float v = (k < K_[l] && n < N_[l]) ? SC_[l]*wsrc[k*N_[l] + n] : 0.f;
        whi[tid] = f2bf(v);
    } else if (tid < 32768 + 528){
        int t = tid - 32768;
        int l = 0;
#pragma unroll
        for (int i=1;i<8;++i) if (t >= BB_[i]) l = i;
        int n = t - BB_[l];
        bo[t] = (n < N_[l]) ? SC_[l]*pa.b[l][n] : 0.f;
    } else if (tid < 33296 + 128){
        int t = tid - 33296;
        if (t < 48)       ws[16912+t]     = CT_*pa.l1w[0][t];
        else if (t < 64)  ws[16960+t-48]  = CT_*pa.l1b[0][t-48];
        else if (t < 112) ws[16976+t-64]  = CT_*pa.l1w[1][t-64];
        else              ws[17024+t-112] = CT_*pa.l1b[1][t-112];
    }
}

// ---------------- layer-1 (3->16, prescaled tanh) on VALU, + K-pad zero of ch16..31
DEV void l1_valu(float x0,float x1,float x2, const float* w, const float* bias,
                 u16* buf, int lane){
    int pxl = lane & 31, jb = (lane>>5)*8;
    float v[8];
#pragma unroll
    for (int j=0;j<8;++j){
        int jj = jb + j;
        v[j] = tanh_ps(bias[jj] + x0*w[jj] + x1*w[16+jj] + x2*w[32+jj]);
    }
    union { u32 d[2]; u64 q; } q0, q1;
    q0.d[0]=cvtpk(v[0],v[1]); q0.d[1]=cvtpk(v[2],v[3]);
    q1.d[0]=cvtpk(v[4],v[5]); q1.d[1]=cvtpk(v[6],v[7]);
    *(u64*)(buf + pxl*132 + jb)      = q0.q;
    *(u64*)(buf + pxl*132 + jb+4)    = q1.q;
    *(u64*)(buf + pxl*132 + 16+jb)   = 0ull;   // zero ch16..31 (layer-2 K-pad)
    *(u64*)(buf + pxl*132 + 16+jb+4) = 0ull;
}

// ---------------- swapped MFMA layer, IN-PLACE on one [32][132] buffer
// A=weights: row=out-ch=lane&15(+ct*16), k=(lane>>4)*8+i
// B=acts:    col=pixel=lane&15(+pt*16),  k=(lane>>4)*8+i
// D: col=pixel=lane&15, row=out-ch=(lane>>4)*4+r (+ct*16) -> cvt_pk x2 + ds_write_b64
// All reads complete (program order + may-alias) before writes -> in-place safe.
// ACT: 0=tanh_ps, 1=sigm_ps, 2=raw channel0 -> sPre[px]
template<int KT, int CT, int ACT>
DEV void layer(u16* buf, const u16* wf, const float* bias, float* sPre, int lane){
    short8 x[2][KT];
    int col = lane & 15, koff = (lane>>4)<<3;
#pragma unroll
    for (int pt=0;pt<2;++pt)
#pragma unroll
    for (int kt=0;kt<KT;++kt)
        x[pt][kt] = ld8(buf + (pt*16 + col)*132 + kt*32 + koff);
    asm volatile("" ::: "memory");   // pin read-before-write (in-place update)
#pragma unroll 2
    for (int ct=0; ct<CT; ++ct){
        f32x4 acc[2];
        acc[0]=(f32x4){0.f,0.f,0.f,0.f};
        acc[1]=(f32x4){0.f,0.f,0.f,0.f};
#pragma unroll
        for (int kt=0;kt<KT;++kt){
            short8 wv = *(const short8*)(wf + (((kt*CT+ct)<<6) + lane)*8);
#pragma unroll
            for (int pt=0;pt<2;++pt) acc[pt] = mfma16(wv, x[pt][kt], acc[pt]);
        }
        if constexpr (ACT==2){
            float v0 = acc[0][0] + bias[0];
            float v1 = acc[1][0] + bias[0];
            if ((lane>>4)==0){ sPre[col]=v0; sPre[16+col]=v1; }
        } else {
            int chb = ct*16 + ((lane>>4)<<2);
            float4 bv = *(const float4*)(bias + chb);
#pragma unroll
            for (int pt=0;pt<2;++pt){
                float v0 = acc[pt][0] + bv.x;
                float v1 = acc[pt][1] + bv.y;
                float v2 = acc[pt][2] + bv.z;
                float v3 = acc[pt][3] + bv.w;
                if constexpr (ACT==0){
                    v0=tanh_ps(v0); v1=tanh_ps(v1); v2=tanh_ps(v2); v3=tanh_ps(v3);
                } else {
                    v0=sigm_ps(v0); v1=sigm_ps(v1); v2=sigm_ps(v2); v3=sigm_ps(v3);
                }
                union { u32 d[2]; u64 q; } qq;
                qq.d[0]=cvtpk(v0,v1); qq.d[1]=cvtpk(v2,v3);
                *(u64*)(buf + (pt*16 + col)*132 + chb) = qq.q;
            }
        }
    }
}

__global__ __launch_bounds__(64, 4)
void dlut_kernel(const float* __restrict__ df, const float* __restrict__ lr,
                 const float* __restrict__ ws, float* __restrict__ out){
    constexpr int Hh=359, Ww=639, HW=Hh*Ww, NP=2*HW, LHW=360*640;
    __shared__ u16 sX[32][132];     // single in-place activation buffer
    __shared__ float sPre[32];

    const u16* whi = (const u16*)ws;
    const float* bo = ws + 16384;

    int lane = threadIdx.x;
    int pxl = lane & 31, hv = lane >> 5;
    int p = blockIdx.x * 32 + pxl;

    float x0=0.f, x1=0.f, x2=0.f;
    int b=0, r2=0, hh=0, wwp=0;
    if (p < NP){
        b = p/HW; r2 = p - b*HW; hh = r2/Ww; wwp = r2 - hh*Ww;
        x0 = df[(b*3+0)*HW + r2];
        x1 = df[(b*3+1)*HW + r2];
        x2 = df[(b*3+2)*HW + r2];
    }

    // ===== MLP2 (scale head) =====
    l1_valu(x0,x1,x2, ws+16976, ws+17024, &sX[0][0], lane);
    __syncthreads();
    layer<1,2,0>(&sX[0][0], whi+19456, bo+288, sPre, lane);
    __syncthreads();
    layer<1,4,0>(&sX[0][0], whi+20480, bo+320, sPre, lane);
    __syncthreads();
    layer<2,8,0>(&sX[0][0], whi+22528, bo+384, sPre, lane);
    __syncthreads();
    layer<4,1,2>(&sX[0][0], whi+30720, bo+512, sPre, lane);
    __syncthreads();
    // ===== MLP1 (F_r head) =====
    l1_valu(x0,x1,x2, ws+16912, ws+16960, &sX[0][0], lane);
    __syncthreads();
    layer<1,2,0>(&sX[0][0], whi+0,     bo+0,   sPre, lane);
    __syncthreads();
    layer<1,4,0>(&sX[0][0], whi+1024,  bo+32,  sPre, lane);
    __syncthreads();
    layer<2,8,0>(&sX[0][0], whi+3072,  bo+96,  sPre, lane);
    __syncthreads();
    layer<4,4,1>(&sX[0][0], whi+11264, bo+224, sPre, lane);
    __syncthreads();
    // Fr (sigmoid'd bf16) in sX[px][0..63]; prescaled s pre-act in sPre[px]

    // ===== filters (separable Gaussian powers) + unfold + writes =====
    if (p < NP){
        float s = sigm_ps(sPre[pxl]) + 0.05f;
        // g = exp(-d2/(2s)) = E1^(16*d2), E1 = 2^(-log2e/(32 s)); 16*dy^2 in {1,9,25,49}
        float E1 = ex2(-0.045084220f * rcpf_(s));
        float F2=E1*E1, F4=F2*F2, F8=F4*F4, F16=F8*F8, F32=F16*F16;
        float F9=F8*E1, F25=F16*F9, F49=F32*F16*E1;
        // cy=1.25 -> rows {F25,E1,F9,F49}; cy=1.75 -> rows {F49,F9,E1,F25}
        bool hb = (hv!=0);          // d = hv*2+dd: dy-set = hv, dx-set = dd
        float ry[4];
        ry[0]= hb?F49:F25; ry[1]= hb?F9:E1; ry[2]= hb?E1:F9; ry[3]= hb?F25:F49;
        float cx0[4] = {F25,E1,F9,F49};
        float cx1[4] = {F49,F9,E1,F25};

        float pvv[3][16];
#pragma unroll
        for (int ky=0;ky<4;++ky){
            int yy=hh+ky-1;
            int yyc = yy<0?0:(yy>359?359:yy);
            bool oky = (yy>=0)&&(yy<360);
#pragma unroll
            for (int kx=0;kx<4;++kx){
                int xx=wwp+kx-1;
                int xxc = xx<0?0:(xx>639?639:xx);
                bool ok = oky&&(xx>=0)&&(xx<640);
                int k=ky*4+kx;
                int base = (b*3)*LHW + yyc*640 + xxc;
#pragma unroll
                for (int c=0;c<3;++c){
                    float v = lr[base + c*LHW];
                    pvv[c][k] = ok ? v : 0.f;
                }
            }
        }
#pragma unroll
        for (int dd=0; dd<2; ++dd){
            int d = hv*2 + dd;
            float t[16]; float gs=0.f, T=0.f;
#pragma unroll
            for (int k=0;k<16;++k){
                float cxv = (dd==0) ? cx0[k&3] : cx1[k&3];   // static index
                float gk = ry[k>>2]*cxv;
                float fr = bf2f(sX[pxl][d*16+k]);
                float tk = gk*fr;
                gs += gk; T += tk;
                t[k] = tk;
            }
            // filt = g*fr/(T) * (exact s16 = rg*T + 1e-12 kept for output & final norm)
            float rg = rcpf_(gs + 1e-12f);
            float s16v = T*rg + 1e-12f;
            float sc2 = rg * rcpf_(s16v);
            float y0=0.f,y1=0.f,y2=0.f;
#pragma unroll
            for (int k=0;k<16;++k){
                y0+=pvv[0][k]*t[k]; y1+=pvv[1][k]*t[k]; y2+=pvv[2][k]*t[k];
            }
            y0*=sc2; y1*=sc2; y2*=sc2;
            int dy=d>>1, dx=d&1;
            int rc = (2*hh+dy)*1278 + 2*wwp+dx;
            out[((b*3+0)*718)*1278 + rc] = y0;
            out[((b*3+1)*718)*1278 + rc] = y1;
            out[((b*3+2)*718)*1278 + rc] = y2;
            out[5505624 + ((b*4+d)*359 + hh)*639 + wwp] = s16v;
        }
    }
}

extern "C" void kernel_launch(void* const* d_in, const int* in_sizes, int n_in,
                              void* d_out, int out_size, void* d_ws, size_t ws_size,
                              hipStream_t stream){
    const float* df=(const float*)d_in[0];
    const float* lr=(const float*)d_in[1];
    // dict order per i: m1_w i -> d_in[2+4i], m1_b i -> [3+4i], m2_w i -> [4+4i], m2_b i -> [5+4i]
    PrepArgs pa;
    for (int i=0;i<4;++i){
        pa.w[i]   = (const float*)d_in[2+4*(i+1)];   // m1_w1..m1_w4
        pa.b[i]   = (const float*)d_in[3+4*(i+1)];   // m1_b1..m1_b4
        pa.w[4+i] = (const float*)d_in[4+4*(i+1)];   // m2_w1..m2_w4
        pa.b[4+i] = (const float*)d_in[5+4*(i+1)];   // m2_b1..m2_b4
    }
    pa.l1w[0] = (const float*)d_in[2];  pa.l1b[0] = (const float*)d_in[3];
    pa.l1w[1] = (const float*)d_in[4];  pa.l1b[1] = (const float*)d_in[5];

    float* ws = (float*)d_ws;
    hipLaunchKernelGGL(prep_kernel, dim3(131), dim3(256), 0, stream, pa, ws);

    constexpr int NP = 2*359*639;
    hipLaunchKernelGGL(dlut_kernel, dim3((NP+31)/32), dim3(64), 0, stream,
                       df, lr, (const float*)ws, (float*)d_out);
}